// Round 9
// baseline (432.490 us; speedup 1.0000x reference)
//
#include <hip/hip_runtime.h>
#include <math.h>

// Problem: NERRelationModel_84963043050124
// B=64 S=512 H=768 E=32 P=16 K=9 R=6 HEADS=4 C1=128 C2=64 FEAT=257
// Outputs: ner_logits [B,S,K]=294912, z [R,B,P]=6144, total [1] -> 301057 f32

#define NB 64
#define NS 512
#define NH 768
#define NE 32
#define NP 16
#define NK 9
#define NR 6
#define NHEADS 4
#define NC1 128
#define NC2 64
#define SEGS 16
#define SEGLEN 32

#define ZOFF 294912
#define TOTOFF 301056

// ---- workspace layout (float offsets) ----
#define WS_ENT   0u           // bf16 entb [B,E,768] (dead after k_mg -> WRT/WFET/SEG)
#define WS_WG1T  1572864u     // bf16 wg1t [512][768]
#define WS_X1    2621440u     // bf16 x1b [B,E,512]
#define WS_X2    3801088u     // f32 [B,E,64]
#define WS_WG2T  3956736u     // bf16 wg2t [64][512]
#define WS_FE    4222976u     // bf16 [B,P,512]
#define WS_CRF   4747264u     // [64]
#define WS_REL   4747328u     // [1]
#define WS_W1T   4747392u     // bf16 [256][768]
// overlapped into dead ENT region (valid after k_mg consumed entb):
#define WS_WRT   0u           // bf16 [R*256][512]
#define WS_WFET  393216u      // bf16 [512][320]
#define WS_SEG   475136u      // f32 [B][SEGS][81]

typedef __attribute__((ext_vector_type(8))) short bf16x8;
typedef __attribute__((ext_vector_type(4))) float f32x4;

__device__ __forceinline__ unsigned short f2bf(float x) {
  union { float f; unsigned u; } v; v.f = x;
  unsigned r = v.u + 0x7FFFu + ((v.u >> 16) & 1u);
  return (unsigned short)(r >> 16);
}

__device__ __forceinline__ float logsigf(float x) {
  if (x >= 0.f) return -log1pf(__expf(-x));
  return x - log1pf(__expf(x));
}

// ---------------- k_prep: weight transposes (w_ner1/w_gat1/w_gat2) + entity pool ----------------
// blocks 0..7: w1t; 8..23: wg1t; 24..25: wg2t; 26..2073: ent pool -> entb bf16.
__global__ __launch_bounds__(256) void k_prep(
    const float* __restrict__ w1, const float* __restrict__ wg1,
    const float* __restrict__ wg2, const float* __restrict__ seq,
    const int* __restrict__ est, const int* __restrict__ elen,
    unsigned short* __restrict__ w1t, unsigned short* __restrict__ wg1t,
    unsigned short* __restrict__ wg2t, unsigned short* __restrict__ entb) {
  __shared__ unsigned short tr[32 * 776];  // [col-in-tile][k]
  const int bid = blockIdx.x, t = threadIdx.x;
  if (bid < 26) {
    const float* src;
    unsigned short* dst;
    int c0, ncol, nkt, kdim;
    if (bid < 8)       { src = w1;  dst = w1t;  ncol = 256; c0 = bid * 32;        nkt = 24; kdim = 768; }
    else if (bid < 24) { src = wg1; dst = wg1t; ncol = 512; c0 = (bid - 8) * 32;  nkt = 24; kdim = 768; }
    else               { src = wg2; dst = wg2t; ncol = 64;  c0 = (bid - 24) * 32; nkt = 16; kdim = 512; }
    for (int p = 0; p < nkt; p++) {
      const int k = p * 32 + (t >> 3), c4 = t & 7;
      const float4 f = *reinterpret_cast<const float4*>(&src[(size_t)k * ncol + c0 + c4 * 4]);
      tr[(c4 * 4 + 0) * 776 + k] = f2bf(f.x);
      tr[(c4 * 4 + 1) * 776 + k] = f2bf(f.y);
      tr[(c4 * 4 + 2) * 776 + k] = f2bf(f.z);
      tr[(c4 * 4 + 3) * 776 + k] = f2bf(f.w);
    }
    __syncthreads();
    const int c = t >> 3, q = t & 7;
    const int chunk = kdim >> 3;  // 96 or 64 k per q
    for (int i = 0; i < (chunk >> 3); i++) {
      *reinterpret_cast<uint4*>(&dst[(size_t)(c0 + c) * kdim + q * chunk + i * 8]) =
          *reinterpret_cast<const uint4*>(&tr[c * 776 + q * chunk + i * 8]);
    }
  } else {
    const int be = bid - 26;
    const int b = be >> 5, e = be & 31;
    const int st = est[b * NE + e];
    int en = st + elen[b * NE + e];
    en = min(max(en, 0), NS - 1);
    const float inv = 1.f / (float)(en - st + 1);
    for (int c = t; c < NH; c += 256) {
      float s = 0.f;
      for (int r = st; r <= en; r++) s += seq[((size_t)b * NS + r) * NH + c];
      entb[((size_t)b * NE + e) * NH + c] = f2bf(s * inv);
    }
  }
}

// ---------------- k_mg: fused GAT1 (blocks 0..255) + NER head (256..1279) ----------------
// GAT1 softmax scratch moved to LDS (no lg[32] reg array) + launch_bounds(256,4)
// caps VGPR at 128 so both branches share a 4-blocks/CU allocation (R7 lesson).
__global__ __launch_bounds__(256, 4) void k_mg(
    const float* __restrict__ seq, const unsigned short* __restrict__ w1t,
    const float* __restrict__ b1, const float* __restrict__ w2,
    const float* __restrict__ b2, float* __restrict__ out,
    const unsigned short* __restrict__ entb, const unsigned short* __restrict__ wg1t,
    const float* __restrict__ as1, const float* __restrict__ ad1,
    const unsigned char* __restrict__ adj, const float* __restrict__ bias1,
    unsigned short* __restrict__ x1b) {
  __shared__ __align__(16) char smem[34304];
  const int bid = blockIdx.x, t = threadIdx.x;
  const int w = t >> 6, lane = t & 63, quad = lane >> 4, l15 = lane & 15;

  if (bid < 256) {
    // ======== fused GAT1: MFMA GEMM + dots + softmax + aggregate + relu, bf16 out ========
    unsigned short* As = (unsigned short*)smem;            // [32*40]
    unsigned short* Bs = (unsigned short*)(smem + 2560);   // [128*40]
    float* Hs  = (float*)(smem + 12800);                   // [32*132]
    float* Att = (float*)(smem + 29696);                   // [32*32] ([j][i])
    float* Sv  = (float*)(smem + 33792);                   // [32]
    float* Dv  = (float*)(smem + 33920);                   // [32]
    const int b = bid >> 2, hd = bid & 3;

    f32x4 acc[2][2];
#pragma unroll
    for (int r = 0; r < 2; r++)
#pragma unroll
      for (int c = 0; c < 2; c++) acc[r][c] = (f32x4){0.f, 0.f, 0.f, 0.f};

    const int rowA = t >> 2, koffA = (t & 3) * 8;  // t<128 stages A
    const unsigned short* aptr = entb + ((size_t)(b * NE) + rowA) * NH + koffA;

    for (int kt = 0; kt < NH; kt += 32) {
      __syncthreads();
      if (t < 128) {
        *reinterpret_cast<uint4*>(&As[rowA * 40 + koffA]) =
            *reinterpret_cast<const uint4*>(aptr + kt);
      }
#pragma unroll
      for (int i = 0; i < 2; i++) {
        const int q = t + 256 * i;
        const int col = q >> 2, koff = (q & 3) * 8;
        *reinterpret_cast<uint4*>(&Bs[col * 40 + koff]) =
            *reinterpret_cast<const uint4*>(&wg1t[(size_t)(hd * 128 + col) * NH + kt + koff]);
      }
      __syncthreads();
      bf16x8 a[2], bb[2];
#pragma unroll
      for (int r = 0; r < 2; r++)
        a[r] = *reinterpret_cast<const bf16x8*>(&As[(r * 16 + l15) * 40 + quad * 8]);
#pragma unroll
      for (int c = 0; c < 2; c++)
        bb[c] = *reinterpret_cast<const bf16x8*>(&Bs[(w * 32 + c * 16 + l15) * 40 + quad * 8]);
#pragma unroll
      for (int r = 0; r < 2; r++)
#pragma unroll
        for (int c = 0; c < 2; c++)
          acc[r][c] = __builtin_amdgcn_mfma_f32_16x16x32_bf16(a[r], bb[c], acc[r][c], 0, 0, 0);
    }
#pragma unroll
    for (int r = 0; r < 2; r++)
#pragma unroll
      for (int c = 0; c < 2; c++)
#pragma unroll
        for (int reg = 0; reg < 4; reg++)
          Hs[(r * 16 + quad * 4 + reg) * 132 + w * 32 + c * 16 + l15] = acc[r][c][reg];
    __syncthreads();
    {
      const int e = t >> 3, cg = t & 7;
      float sv = 0.f, dv = 0.f;
#pragma unroll
      for (int c = 0; c < 16; c++) {
        const float h = Hs[e * 132 + cg * 16 + c];
        sv += h * as1[hd * NC1 + cg * 16 + c];
        dv += h * ad1[hd * NC1 + cg * 16 + c];
      }
#pragma unroll
      for (int o = 1; o < 8; o <<= 1) { sv += __shfl_xor(sv, o); dv += __shfl_xor(dv, o); }
      if (cg == 0) { Sv[e] = sv; Dv[e] = dv; }
    }
    __syncthreads();
    if (t < 32) {
      // 3-pass softmax with Att as scratch (no 32-reg array -> low VGPR)
      const int i = t;
      const float di = Dv[i];
      float m = -1e30f;
      for (int j = 0; j < 32; j++) {
        float v = di + Sv[j];
        v = v >= 0.f ? v : 0.2f * v;
        if (!adj[((size_t)b * NE + i) * NE + j]) v = -1e9f;
        Att[j * 32 + i] = v;
        m = fmaxf(m, v);
      }
      float sum = 0.f;
      for (int j = 0; j < 32; j++) {
        const float e = __expf(Att[j * 32 + i] - m);
        Att[j * 32 + i] = e;
        sum += e;
      }
      const float inv = 1.f / sum;
      for (int j = 0; j < 32; j++) Att[j * 32 + i] *= inv;
    }
    __syncthreads();
    {
      const int tc = t & 31, tr2 = t >> 5;
#pragma unroll
      for (int i = 0; i < 4; i++) {
        const int row = tr2 * 4 + i;
        float o0 = bias1[hd * NC1 + tc * 4 + 0];
        float o1 = bias1[hd * NC1 + tc * 4 + 1];
        float o2 = bias1[hd * NC1 + tc * 4 + 2];
        float o3 = bias1[hd * NC1 + tc * 4 + 3];
#pragma unroll
        for (int j = 0; j < 32; j++) {
          const float a = Att[j * 32 + row];
          o0 = fmaf(a, Hs[j * 132 + tc * 4 + 0], o0);
          o1 = fmaf(a, Hs[j * 132 + tc * 4 + 1], o1);
          o2 = fmaf(a, Hs[j * 132 + tc * 4 + 2], o2);
          o3 = fmaf(a, Hs[j * 132 + tc * 4 + 3], o3);
        }
        uint2 v;
        v.x = (unsigned)f2bf(fmaxf(o0, 0.f)) | ((unsigned)f2bf(fmaxf(o1, 0.f)) << 16);
        v.y = (unsigned)f2bf(fmaxf(o2, 0.f)) | ((unsigned)f2bf(fmaxf(o3, 0.f)) << 16);
        *reinterpret_cast<uint2*>(&x1b[((size_t)b * NE + row) * 512 + hd * 128 + tc * 4]) = v;
      }
    }
  } else {
    // ======== NER head: MFMA bf16, 32-token x 256-col tiles (proven structure) ========
    unsigned short* AsS = (unsigned short*)smem;           // [32*40]
    unsigned short* BsS = (unsigned short*)(smem + 2560);  // [256*40]
    float* zs = (float*)(smem + 23040);                    // [32*4*12]
    const int tok0 = (bid - 256) * 32;

    f32x4 acc[2][4];
#pragma unroll
    for (int r = 0; r < 2; r++)
#pragma unroll
      for (int c = 0; c < 4; c++) acc[r][c] = (f32x4){0.f, 0.f, 0.f, 0.f};

    const int tokA = t >> 3, koffA = (t & 7) * 4;  // 4 floats per thread
    const float* aptr = seq + (size_t)(tok0 + tokA) * NH + koffA;

    for (int kt = 0; kt < NH; kt += 32) {
      __syncthreads();
      {
        const float4 f0 = *reinterpret_cast<const float4*>(aptr + kt);
        uint2 v;
        v.x = (unsigned)f2bf(f0.x) | ((unsigned)f2bf(f0.y) << 16);
        v.y = (unsigned)f2bf(f0.z) | ((unsigned)f2bf(f0.w) << 16);
        *reinterpret_cast<uint2*>(&AsS[tokA * 40 + koffA]) = v;
      }
#pragma unroll
      for (int i = 0; i < 4; i++) {
        const int q = t + 256 * i;
        const int col = q >> 2, koff = (q & 3) * 8;
        *reinterpret_cast<uint4*>(&BsS[col * 40 + koff]) =
            *reinterpret_cast<const uint4*>(&w1t[(size_t)col * NH + kt + koff]);
      }
      __syncthreads();
      bf16x8 a[2], b[4];
#pragma unroll
      for (int r = 0; r < 2; r++)
        a[r] = *reinterpret_cast<const bf16x8*>(&AsS[(r * 16 + l15) * 40 + quad * 8]);
#pragma unroll
      for (int c = 0; c < 4; c++)
        b[c] = *reinterpret_cast<const bf16x8*>(&BsS[(w * 64 + c * 16 + l15) * 40 + quad * 8]);
#pragma unroll
      for (int r = 0; r < 2; r++)
#pragma unroll
        for (int c = 0; c < 4; c++)
          acc[r][c] = __builtin_amdgcn_mfma_f32_16x16x32_bf16(a[r], b[c], acc[r][c], 0, 0, 0);
    }

    float b1v[4], w2v[4][NK];
#pragma unroll
    for (int c = 0; c < 4; c++) {
      const int col = w * 64 + c * 16 + l15;
      b1v[c] = b1[col];
#pragma unroll
      for (int cc = 0; cc < NK; cc++) w2v[c][cc] = w2[col * NK + cc];
    }
#pragma unroll
    for (int r = 0; r < 2; r++) {
#pragma unroll
      for (int reg = 0; reg < 4; reg++) {
        float p[NK];
#pragma unroll
        for (int cc = 0; cc < NK; cc++) p[cc] = 0.f;
#pragma unroll
        for (int c = 0; c < 4; c++) {
          const float h = fmaxf(acc[r][c][reg] + b1v[c], 0.f);
#pragma unroll
          for (int cc = 0; cc < NK; cc++) p[cc] = fmaf(h, w2v[c][cc], p[cc]);
        }
#pragma unroll
        for (int o = 1; o < 16; o <<= 1)
#pragma unroll
          for (int cc = 0; cc < NK; cc++) p[cc] += __shfl_xor(p[cc], o);
        if (l15 == 0) {
          const int tokr = r * 16 + quad * 4 + reg;
#pragma unroll
          for (int cc = 0; cc < NK; cc++) zs[(tokr * 4 + w) * 12 + cc] = p[cc];
        }
      }
    }
    __syncthreads();
    if (t < 32) {
#pragma unroll
      for (int cc = 0; cc < NK; cc++) {
        const float z = zs[(t * 4 + 0) * 12 + cc] + zs[(t * 4 + 1) * 12 + cc] +
                        zs[(t * 4 + 2) * 12 + cc] + zs[(t * 4 + 3) * 12 + cc] + b2[cc];
        out[(size_t)(tok0 + t) * NK + cc] = z;
      }
    }
  }
}

// ---------------- k_mid: weight converts (blocks 0..57) + CRF segment reduce (58..1081) ----------------
// CRF log-semiring products exp-factored: lse_m(A[i,m]+B[m,j]) = mxA_i + mxB_j +
// log(sum exp(A-mxA)*exp(B-mxB)) -> 162 exp + 729 fma per product vs 729 exp.
__global__ __launch_bounds__(256) void k_mid(
    const float* __restrict__ wrc, const float* __restrict__ wfe,
    unsigned short* __restrict__ wrt, unsigned short* __restrict__ wfet,
    const float* __restrict__ em, const int* __restrict__ mask,
    const float* __restrict__ trans, float* __restrict__ segm) {
  __shared__ __align__(16) char smem[36864];
  const int bid = blockIdx.x, t = threadIdx.x;
  if (bid < 58) {
    unsigned short* tr = (unsigned short*)smem;  // [256*72]
    if (bid < 48) {
      const int r = bid >> 3, kt = bid & 7;
      const int k0 = kt * 64;
#pragma unroll
      for (int i = 0; i < 16; i++) {
        const int slot = t + 256 * i;
        const int row = slot >> 6, c4 = slot & 63;
        const float4 f = *reinterpret_cast<const float4*>(
            &wrc[((size_t)(r * 512) + k0 + row) * 256 + c4 * 4]);
        tr[(c4 * 4 + 0) * 72 + row] = f2bf(f.x);
        tr[(c4 * 4 + 1) * 72 + row] = f2bf(f.y);
        tr[(c4 * 4 + 2) * 72 + row] = f2bf(f.z);
        tr[(c4 * 4 + 3) * 72 + row] = f2bf(f.w);
      }
      __syncthreads();
#pragma unroll
      for (int i = 0; i < 8; i++) {
        const int slot = t + 256 * i;
        const int col = slot >> 3, q = slot & 7;
        *reinterpret_cast<uint4*>(&wrt[((size_t)(r * 256 + col)) * 512 + k0 + q * 8]) =
            *reinterpret_cast<const uint4*>(&tr[col * 72 + q * 8]);
      }
    } else {
      const int b2 = bid - 48;
      const int kt = b2 % 5, cb = b2 / 5;
      const int k0 = kt * 64, c0 = cb * 256;
#pragma unroll
      for (int i = 0; i < 16; i++) {
        const int slot = t + 256 * i;
        const int row = slot >> 6, c4 = slot & 63;
        const int k = k0 + row;
        float4 f = {0.f, 0.f, 0.f, 0.f};
        if (k < 257)
          f = *reinterpret_cast<const float4*>(&wfe[(size_t)k * 512 + c0 + c4 * 4]);
        tr[(c4 * 4 + 0) * 72 + row] = f2bf(f.x);
        tr[(c4 * 4 + 1) * 72 + row] = f2bf(f.y);
        tr[(c4 * 4 + 2) * 72 + row] = f2bf(f.z);
        tr[(c4 * 4 + 3) * 72 + row] = f2bf(f.w);
      }
      __syncthreads();
#pragma unroll
      for (int i = 0; i < 8; i++) {
        const int slot = t + 256 * i;
        const int col = slot >> 3, q = slot & 7;
        *reinterpret_cast<uint4*>(&wfet[((size_t)(c0 + col)) * 320 + k0 + q * 8]) =
            *reinterpret_cast<const uint4*>(&tr[col * 72 + q * 8]);
      }
    }
  } else {
    float* bufA = (float*)smem;              // [16*81]
    float* bufB = (float*)(smem + 5184);     // [8*81]
    float* EA   = (float*)(smem + 7776);     // [8*81]
    float* EB   = (float*)(smem + 10368);    // [8*81]
    float* Gf   = (float*)(smem + 12960);    // [16*81]
    float* ems  = (float*)(smem + 18144);    // [32*9]
    float* trs  = (float*)(smem + 19296);    // [81]
    float* Hexp = (float*)(smem + 19620);    // [81]
    float* mxp  = (float*)(smem + 19944);    // [16*9]
    float* mxA  = (float*)(smem + 20520);    // [8*9]
    float* mxB  = (float*)(smem + 20808);    // [8*9]
    int*   mks  = (int*)(smem + 21096);      // [32]
    const int blk = bid - 58;
    const int b = blk >> 4, seg = blk & 15;
    const int s0 = 1 + seg * SEGLEN;
    const float* emb = em + (size_t)b * NS * NK;
    const int* mk = mask + b * NS;
    if (t < 81) { trs[t] = trans[t]; Hexp[t] = __expf(trans[t]); }
    for (int i = t; i < SEGLEN * 9; i += 256) {
      const int g = s0 * 9 + i;
      ems[i] = (g < NS * 9) ? emb[g] : 0.f;
    }
    if (t < SEGLEN) {
      const int s = s0 + t;
      mks[t] = (s < NS) ? mk[s] : 0;
    }
    __syncthreads();
    // leaf row maxes: mxp[p][i] = max_m trs[i,m]+ems[2p,m]
    for (int idx = t; idx < 144; idx += 256) {
      const int p = idx / 9, i = idx - p * 9;
      const float* eml = &ems[(2 * p) * 9];
      float mx = -1e30f;
#pragma unroll
      for (int m = 0; m < 9; m++) mx = fmaxf(mx, trs[i * 9 + m] + eml[m]);
      mxp[idx] = mx;
    }
    __syncthreads();
    // G[p][i][m] = exp(trs[i,m]+ems[2p,m]-mxp[p][i])
    for (int idx = t; idx < 1296; idx += 256) {
      const int p = idx / 81, r81 = idx - p * 81, i = r81 / 9, m = r81 - i * 9;
      Gf[idx] = __expf(trs[i * 9 + m] + ems[(2 * p) * 9 + m] - mxp[p * 9 + i]);
    }
    __syncthreads();
    // leaves
    for (int idx = t; idx < 1296; idx += 256) {
      const int p = idx / 81, e = idx - p * 81, i = e / 9, j = e - i * 9;
      const int la = 2 * p, lb = la + 1;
      const bool ma = mks[la] > 0, mb = mks[lb] > 0;
      float r;
      if (ma && mb) {
        float s = 0.f;
#pragma unroll
        for (int m = 0; m < 9; m++) s = fmaf(Gf[p * 81 + i * 9 + m], Hexp[m * 9 + j], s);
        r = mxp[p * 9 + i] + __logf(s) + ems[lb * 9 + j];
      } else if (ma) {
        r = trs[e] + ems[la * 9 + j];
      } else if (mb) {
        r = trs[e] + ems[lb * 9 + j];
      } else {
        r = (i == j) ? 0.f : -1e30f;
      }
      bufA[idx] = r;
    }
    // tree combines (exp-factored)
    float* src = bufA;
    float* dst = bufB;
    for (int n = 16; n > 1; n >>= 1) {
      const int half = n >> 1;
      __syncthreads();
      for (int idx = t; idx < half * 18; idx += 256) {
        const int q = idx / 18, r2 = idx - q * 18;
        if (r2 < 9) {
          const float* A = src + (size_t)(2 * q) * 81 + r2 * 9;
          float mx = -1e30f;
#pragma unroll
          for (int m = 0; m < 9; m++) mx = fmaxf(mx, A[m]);
          mxA[q * 9 + r2] = mx;
        } else {
          const int j = r2 - 9;
          const float* Bm = src + (size_t)(2 * q + 1) * 81;
          float mx = -1e30f;
#pragma unroll
          for (int m = 0; m < 9; m++) mx = fmaxf(mx, Bm[m * 9 + j]);
          mxB[q * 9 + j] = mx;
        }
      }
      __syncthreads();
      for (int idx = t; idx < half * 81; idx += 256) {
        const int q = idx / 81, e = idx - q * 81, i = e / 9, c = e - i * 9;
        EA[idx] = __expf(src[(size_t)(2 * q) * 81 + e] - mxA[q * 9 + i]);
        EB[idx] = __expf(src[(size_t)(2 * q + 1) * 81 + e] - mxB[q * 9 + c]);
      }
      __syncthreads();
      for (int idx = t; idx < half * 81; idx += 256) {
        const int q = idx / 81, e = idx - q * 81, i = e / 9, j = e - i * 9;
        float s = 0.f;
#pragma unroll
        for (int m = 0; m < 9; m++) s = fmaf(EA[q * 81 + i * 9 + m], EB[q * 81 + m * 9 + j], s);
        dst[idx] = mxA[q * 9 + i] + mxB[q * 9 + j] + __logf(s);
      }
      float* tmp = src; src = dst; dst = tmp;
    }
    __syncthreads();
    if (t < 81) segm[((size_t)b * SEGS + seg) * 81 + t] = src[t];
  }
}

// ---------------- k_late: fused GAT2 MFMA (blocks 0..63) + CRF finalize (64..127) ----------------
__global__ __launch_bounds__(256) void k_late(
    const unsigned short* __restrict__ x1b, const unsigned short* __restrict__ wg2t,
    const float* __restrict__ as2, const float* __restrict__ ad2,
    const unsigned char* __restrict__ adj, const float* __restrict__ bias2,
    float* __restrict__ x2,
    const float* __restrict__ em, const int* __restrict__ tags,
    const int* __restrict__ mask, const float* __restrict__ startv,
    const float* __restrict__ endv, const float* __restrict__ trans,
    const float* __restrict__ segm, float* __restrict__ lossb) {
  __shared__ __align__(16) char smem[20736];
  const int bid = blockIdx.x, t = threadIdx.x;
  if (bid < 64) {
    unsigned short* As = (unsigned short*)smem;           // [32*40]
    unsigned short* Bs = (unsigned short*)(smem + 2560);  // [64*40]
    float* H2  = (float*)(smem + 7680);                   // [32*68]
    float* Att = (float*)(smem + 16384);                  // [32*32] ([j][i])
    float* Sv  = (float*)(smem + 20480);                  // [32]
    float* Dv  = (float*)(smem + 20608);                  // [32]
    const int b = bid;
    const int w = t >> 6, lane = t & 63, quad = lane >> 4, l15 = lane & 15;

    f32x4 acc[2];
#pragma unroll
    for (int r = 0; r < 2; r++) acc[r] = (f32x4){0.f, 0.f, 0.f, 0.f};

    const int rowA = t >> 2, koffA = (t & 3) * 8;  // t<128 stages A
    const unsigned short* aptr = x1b + ((size_t)(b * NE) + rowA) * 512 + koffA;

    for (int kt = 0; kt < 512; kt += 32) {
      __syncthreads();
      if (t < 128) {
        *reinterpret_cast<uint4*>(&As[rowA * 40 + koffA]) =
            *reinterpret_cast<const uint4*>(aptr + kt);
      }
      {
        const int col = t >> 2, koff = (t & 3) * 8;  // 64 cols x 4 chunks
        *reinterpret_cast<uint4*>(&Bs[col * 40 + koff]) =
            *reinterpret_cast<const uint4*>(&wg2t[(size_t)col * 512 + kt + koff]);
      }
      __syncthreads();
      const bf16x8 a0 = *reinterpret_cast<const bf16x8*>(&As[l15 * 40 + quad * 8]);
      const bf16x8 a1 = *reinterpret_cast<const bf16x8*>(&As[(16 + l15) * 40 + quad * 8]);
      const bf16x8 bb = *reinterpret_cast<const bf16x8*>(&Bs[(w * 16 + l15) * 40 + quad * 8]);
      acc[0] = __builtin_amdgcn_mfma_f32_16x16x32_bf16(a0, bb, acc[0], 0, 0, 0);
      acc[1] = __builtin_amdgcn_mfma_f32_16x16x32_bf16(a1, bb, acc[1], 0, 0, 0);
    }
#pragma unroll
    for (int r = 0; r < 2; r++)
#pragma unroll
      for (int reg = 0; reg < 4; reg++)
        H2[(r * 16 + quad * 4 + reg) * 68 + w * 16 + l15] = acc[r][reg];
    __syncthreads();
    {
      const int e = t >> 3, cg = t & 7;
      float sv = 0.f, dv = 0.f;
#pragma unroll
      for (int c = 0; c < 8; c++) {
        const float h = H2[e * 68 + cg * 8 + c];
        sv += h * as2[cg * 8 + c];
        dv += h * ad2[cg * 8 + c];
      }
#pragma unroll
      for (int o = 1; o < 8; o <<= 1) { sv += __shfl_xor(sv, o); dv += __shfl_xor(dv, o); }
      if (cg == 0) { Sv[e] = sv; Dv[e] = dv; }
    }
    __syncthreads();
    if (t < 32) {
      const int i = t;
      const float di = Dv[i];
      float m = -1e30f;
      for (int j = 0; j < 32; j++) {
        float v = di + Sv[j];
        v = v >= 0.f ? v : 0.2f * v;
        if (!adj[((size_t)b * NE + i) * NE + j]) v = -1e9f;
        Att[j * 32 + i] = v;
        m = fmaxf(m, v);
      }
      float sum = 0.f;
      for (int j = 0; j < 32; j++) {
        const float e = __expf(Att[j * 32 + i] - m);
        Att[j * 32 + i] = e;
        sum += e;
      }
      const float inv = 1.f / sum;
      for (int j = 0; j < 32; j++) Att[j * 32 + i] *= inv;
    }
    __syncthreads();
    {
      const int tc = t & 15, tr2 = t >> 4;
#pragma unroll
      for (int i = 0; i < 2; i++) {
        const int row = tr2 * 2 + i;
        float o0 = bias2[tc * 4 + 0];
        float o1 = bias2[tc * 4 + 1];
        float o2 = bias2[tc * 4 + 2];
        float o3 = bias2[tc * 4 + 3];
#pragma unroll
        for (int j = 0; j < 32; j++) {
          const float a = Att[j * 32 + row];
          o0 = fmaf(a, H2[j * 68 + tc * 4 + 0], o0);
          o1 = fmaf(a, H2[j * 68 + tc * 4 + 1], o1);
          o2 = fmaf(a, H2[j * 68 + tc * 4 + 2], o2);
          o3 = fmaf(a, H2[j * 68 + tc * 4 + 3], o3);
        }
        float4 v;
        v.x = o0; v.y = o1; v.z = o2; v.w = o3;
        *reinterpret_cast<float4*>(&x2[((size_t)b * NE + row) * NC2 + tc * 4]) = v;
      }
    }
  } else {
    float* sm  = (float*)smem;            // [SEGS*81]
    float* av  = (float*)(smem + 5184);   // [16]
    float* red = (float*)(smem + 5248);   // [2]
    const int b = bid - 64;
    const float* emb = em + (size_t)b * NS * NK;
    const int* mk = mask + b * NS;
    const int* tg = tags + b * NS;
    for (int i = t; i < SEGS * 81; i += 256) sm[i] = segm[(size_t)b * SEGS * 81 + i];
    if (t < 64) {
      float num = 0.f;
      int lastS = 0;
#pragma unroll
      for (int o = 0; o < 8; o++) {
        const int s = t * 8 + o;
        if (s >= 1 && mk[s] > 0) {
          const int cur = tg[s], prv = tg[s - 1];
          num += trans[prv * NK + cur] + emb[s * NK + cur];
          lastS = s;
        }
      }
#pragma unroll
      for (int o = 32; o > 0; o >>= 1) {
        num += __shfl_xor(num, o);
        lastS = max(lastS, __shfl_xor(lastS, o));
      }
      if (t == 0) {
        const int t0 = tg[0];
        red[0] = startv[t0] + emb[t0] + num + endv[tg[lastS]];
      }
    }
    __syncthreads();
    if (t < 9) av[t] = startv[t] + emb[t];
    __syncthreads();
    for (int h = 0; h < SEGS; h++) {
      float nv = 0.f;
      if (t < 9) {
        float v[9], mx = -1e30f;
#pragma unroll
        for (int i2 = 0; i2 < 9; i2++) {
          v[i2] = av[i2] + sm[h * 81 + i2 * 9 + t];
          mx = fmaxf(mx, v[i2]);
        }
        float sum = 0.f;
#pragma unroll
        for (int i2 = 0; i2 < 9; i2++) sum += __expf(v[i2] - mx);
        nv = mx + __logf(sum);
      }
      __syncthreads();
      if (t < 9) av[t] = nv;
      __syncthreads();
    }
    if (t == 0) {
      float mx = -1e30f;
#pragma unroll
      for (int j = 0; j < 9; j++) mx = fmaxf(mx, av[j] + endv[j]);
      float sum = 0.f;
#pragma unroll
      for (int j = 0; j < 9; j++) sum += __expf(av[j] + endv[j] - mx);
      lossb[b] = (mx + __logf(sum)) - red[0];
    }
  }
}

// ---------------- k_fe: pair-features (inlined) + MFMA + LN + leaky, bf16 out ----------------
__global__ __launch_bounds__(256) void k_fe(const float* __restrict__ x2,
    const int* __restrict__ pe1, const int* __restrict__ pe2,
    const unsigned short* __restrict__ wt, const float* __restrict__ bfe,
    const float* __restrict__ g, const float* __restrict__ be,
    unsigned short* __restrict__ feb) {
  __shared__ unsigned short Af[16 * 320];
  __shared__ float Cs[16 * 520];
  __shared__ float ctxs[64];
  const int b = blockIdx.x, t = threadIdx.x;
  const int w = t >> 6, lane = t & 63, quad = lane >> 4, l15 = lane & 15;
  if (t < 64) {
    float cs = 0.f;
    for (int e = 0; e < NE; e++) cs += x2[((size_t)b * NE + e) * NC2 + t];
    ctxs[t] = cs * (1.f / NE);
  }
  __syncthreads();
  for (int i = t; i < 16 * 320; i += 256) {
    const int p = i / 320, k = i - p * 320;
    unsigned short o = 0;
    if (k < 260) {
      const int e1 = pe1[b * NP + p], e2 = pe2[b * NP + p];
      float v;
      if (k < 64) v = x2[((size_t)b * NE + e1) * NC2 + k];
      else if (k < 128) v = x2[((size_t)b * NE + e2) * NC2 + (k - 64)];
      else if (k < 192) v = x2[((size_t)b * NE + e1) * NC2 + (k - 128)] *
                            x2[((size_t)b * NE + e2) * NC2 + (k - 128)];
      else if (k < 256) v = ctxs[k - 192];
      else if (k == 256) v = logf(fabsf((float)(e1 - e2)) + 1.f);
      else v = 0.f;
      o = f2bf(v);
    }
    Af[i] = o;
  }
  __syncthreads();
  f32x4 acc[8];
#pragma unroll
  for (int c = 0; c < 8; c++) acc[c] = (f32x4){0.f, 0.f, 0.f, 0.f};
#pragma unroll
  for (int kt = 0; kt < 10; kt++) {
    const bf16x8 a = *reinterpret_cast<const bf16x8*>(&Af[l15 * 320 + kt * 32 + quad * 8]);
#pragma unroll
    for (int c = 0; c < 8; c++) {
      const int col = w * 128 + c * 16 + l15;
      const bf16x8 bv = *reinterpret_cast<const bf16x8*>(&wt[(size_t)col * 320 + kt * 32 + quad * 8]);
      acc[c] = __builtin_amdgcn_mfma_f32_16x16x32_bf16(a, bv, acc[c], 0, 0, 0);
    }
  }
#pragma unroll
  for (int c = 0; c < 8; c++)
#pragma unroll
    for (int reg = 0; reg < 4; reg++)
      Cs[(quad * 4 + reg) * 520 + w * 128 + c * 16 + l15] = acc[c][reg];
  __syncthreads();
  float bfev[8], gv[8], bev[8];
#pragma unroll
  for (int ch = 0; ch < 8; ch++) {
    const int col = ch * 64 + lane;
    bfev[ch] = bfe[col]; gv[ch] = g[col]; bev[ch] = be[col];
  }
#pragma unroll
  for (int pp = 0; pp < 4; pp++) {
    const int p = w * 4 + pp;
    float v[8], s = 0.f, sq = 0.f;
#pragma unroll
    for (int ch = 0; ch < 8; ch++) {
      v[ch] = Cs[p * 520 + ch * 64 + lane] + bfev[ch];
      s += v[ch]; sq += v[ch] * v[ch];
    }
#pragma unroll
    for (int o = 32; o > 0; o >>= 1) { s += __shfl_xor(s, o); sq += __shfl_xor(sq, o); }
    const float mean = s * (1.f / 512.f);
    const float var = sq * (1.f / 512.f) - mean * mean;
    const float rr = rsqrtf(var + 1e-5f);
#pragma unroll
    for (int ch = 0; ch < 8; ch++) {
      float n = (v[ch] - mean) * rr * gv[ch] + bev[ch];
      n = n >= 0.f ? n : 0.01f * n;
      feb[(size_t)(b * NP + p) * 512 + ch * 64 + lane] = f2bf(n);
    }
  }
}

// ---------------- relation heads: MFMA bf16 GEMM + LN + leaky + dot + BCE ----------------
__global__ __launch_bounds__(256) void k_rc(const unsigned short* __restrict__ feb,
    const unsigned short* __restrict__ wrt, const float* __restrict__ b1,
    const float* __restrict__ g, const float* __restrict__ be,
    const float* __restrict__ w2, const float* __restrict__ b2,
    const int* __restrict__ ylab, float* __restrict__ zout, float* __restrict__ relacc) {
  __shared__ unsigned short Af[16 * 520];
  __shared__ float Cs[16 * 264];
  const int blk = blockIdx.x;
  const int r = blk >> 6, b = blk & 63;
  const int t = threadIdx.x;
  const int w = t >> 6, lane = t & 63, quad = lane >> 4, l15 = lane & 15;
#pragma unroll
  for (int i = 0; i < 4; i++) {
    const int slot = t + 256 * i;
    const int p = slot >> 6, q = slot & 63;
    *reinterpret_cast<uint4*>(&Af[p * 520 + q * 8]) =
        *reinterpret_cast<const uint4*>(&feb[(size_t)(b * NP + p) * 512 + q * 8]);
  }
  __syncthreads();
  f32x4 acc[4];
#pragma unroll
  for (int c = 0; c < 4; c++) acc[c] = (f32x4){0.f, 0.f, 0.f, 0.f};
#pragma unroll
  for (int kt = 0; kt < 16; kt++) {
    const bf16x8 a = *reinterpret_cast<const bf16x8*>(&Af[l15 * 520 + kt * 32 + quad * 8]);
#pragma unroll
    for (int c = 0; c < 4; c++) {
      const int col = w * 64 + c * 16 + l15;
      const bf16x8 bv = *reinterpret_cast<const bf16x8*>(
          &wrt[(size_t)(r * 256 + col) * 512 + kt * 32 + quad * 8]);
      acc[c] = __builtin_amdgcn_mfma_f32_16x16x32_bf16(a, bv, acc[c], 0, 0, 0);
    }
  }
#pragma unroll
  for (int c = 0; c < 4; c++)
#pragma unroll
    for (int reg = 0; reg < 4; reg++)
      Cs[(quad * 4 + reg) * 264 + w * 64 + c * 16 + l15] = acc[c][reg];
  __syncthreads();
  float b1v[4], gv[4], bev[4], w2v[4];
#pragma unroll
  for (int ch = 0; ch < 4; ch++) {
    const int col = r * 256 + ch * 64 + lane;
    b1v[ch] = b1[col]; gv[ch] = g[col]; bev[ch] = be[col]; w2v[ch] = w2[col];
  }
  const float b2v = b2[r];
  float local = 0.f;
#pragma unroll
  for (int pp = 0; pp < 4; pp++) {
    const int p = w * 4 + pp;
    float v[4], s = 0.f, sq = 0.f;
#pragma unroll
    for (int ch = 0; ch < 4; ch++) {
      v[ch] = Cs[p * 264 + ch * 64 + lane] + b1v[ch];
      s += v[ch]; sq += v[ch] * v[ch];
    }
#pragma unroll
    for (int o = 32; o > 0; o >>= 1) { s += __shfl_xor(s, o); sq += __shfl_xor(sq, o); }
    const float mean = s * (1.f / 256.f);
    const float var = sq * (1.f / 256.f) - mean * mean;
    const float rr = rsqrtf(var + 1e-5f);
    float zdot = 0.f;
#pragma unroll
    for (int ch = 0; ch < 4; ch++) {
      float n = (v[ch] - mean) * rr * gv[ch] + bev[ch];
      n = n >= 0.f ? n : 0.01f * n;
      zdot = fmaf(n, w2v[ch], zdot);
    }
#pragma unroll
    for (int o = 32; o > 0; o >>= 1) zdot += __shfl_xor(zdot, o);
    if (lane == 0) {
      const float zp = zdot + b2v;
      zout[(size_t)(r * NB + b) * NP + p] = zp;
      const float y = (float)ylab[b * NP + p];
      local += -(2.f * y * logsigf(zp) + (1.f - y) * logsigf(-zp));
    }
  }
  if (lane == 0) atomicAdd(relacc, local * (1.f / (NB * NP)));
}

// ---------------- finalize total loss ----------------
__global__ __launch_bounds__(64) void k_fin(const float* __restrict__ lossb,
    const float* __restrict__ rel, float* __restrict__ out) {
  float v = lossb[threadIdx.x];
#pragma unroll
  for (int o = 32; o > 0; o >>= 1) v += __shfl_down(v, o);
  if (threadIdx.x == 0) out[TOTOFF] = v * (1.f / NB) + rel[0];
}

extern "C" void kernel_launch(void* const* d_in, const int* in_sizes, int n_in,
                              void* d_out, int out_size, void* d_ws, size_t ws_size,
                              hipStream_t stream) {
  const float* seq = (const float*)d_in[0];
  const int* amask = (const int*)d_in[1];
  const int* nlab = (const int*)d_in[2];
  const int* est = (const int*)d_in[3];
  const int* elen = (const int*)d_in[4];
  const int* pe1 = (const int*)d_in[5];
  const int* pe2 = (const int*)d_in[6];
  const int* plab = (const int*)d_in[7];
  const unsigned char* adj = (const unsigned char*)d_in[8];
  const float* w_ner1 = (const float*)d_in[9];
  const float* b_ner1 = (const float*)d_in[10];
  const float* w_ner2 = (const float*)d_in[11];
  const float* b_ner2 = (const float*)d_in[12];
  const float* crf_start = (const float*)d_in[13];
  const float* crf_end = (const float*)d_in[14];
  const float* crf_trans = (const float*)d_in[15];
  const float* w_gat1 = (const float*)d_in[16];
  const float* a_src1 = (const float*)d_in[17];
  const float* a_dst1 = (const float*)d_in[18];
  const float* b_gat1 = (const float*)d_in[19];
  const float* w_gat2 = (const float*)d_in[20];
  const float* a_src2 = (const float*)d_in[21];
  const float* a_dst2 = (const float*)d_in[22];
  const float* b_gat2 = (const float*)d_in[23];
  const float* w_fe = (const float*)d_in[24];
  const float* b_fe = (const float*)d_in[25];
  const float* g_fe = (const float*)d_in[26];
  const float* be_fe = (const float*)d_in[27];
  const float* w_rc1 = (const float*)d_in[28];
  const float* b_rc1 = (const float*)d_in[29];
  const float* g_rc = (const float*)d_in[30];
  const float* be_rc = (const float*)d_in[31];
  const float* w_rc2 = (const float*)d_in[32];
  const float* b_rc2 = (const float*)d_in[33];

  float* out = (float*)d_out;
  float* ws = (float*)d_ws;
  float* x2 = ws + WS_X2;
  float* crfb = ws + WS_CRF;
  float* rel = ws + WS_REL;
  unsigned short* entb = (unsigned short*)(ws + WS_ENT);
  unsigned short* wg1t = (unsigned short*)(ws + WS_WG1T);
  unsigned short* wg2t = (unsigned short*)(ws + WS_WG2T);
  unsigned short* x1b = (unsigned short*)(ws + WS_X1);
  unsigned short* w1t = (unsigned short*)(ws + WS_W1T);
  unsigned short* feb = (unsigned short*)(ws + WS_FE);
  unsigned short* wrt = (unsigned short*)(ws + WS_WRT);    // dead ENT region
  unsigned short* wfet = (unsigned short*)(ws + WS_WFET);  // dead ENT region
  float* segm = ws + WS_SEG;                               // dead ENT region

  hipMemsetAsync(rel, 0, sizeof(float), stream);

  // 1) weight transposes + entity pooling (independent)
  k_prep<<<2074, 256, 0, stream>>>(w_ner1, w_gat1, w_gat2, seq, est, elen,
                                   w1t, wg1t, wg2t, entb);
  // 2) GAT1 + NER merged, both capped at <=128 VGPR -> 4 blocks/CU co-residency
  k_mg<<<1280, 256, 0, stream>>>(seq, w1t, b_ner1, w_ner2, b_ner2, out,
                                 entb, wg1t, a_src1, a_dst1, adj, b_gat1, x1b);
  // 3) weight converts (ENT region now dead) + CRF segment reduce (exp-factored)
  k_mid<<<1082, 256, 0, stream>>>(w_rc1, w_fe, wrt, wfet, out, amask, crf_trans, segm);
  // 4) GAT2 MFMA + CRF finalize, co-resident
  k_late<<<128, 256, 0, stream>>>(x1b, wg2t, a_src2, a_dst2, adj, b_gat2, x2,
                                  out, nlab, amask, crf_start, crf_end, crf_trans,
                                  segm, crfb);
  // 5) pair features (inlined) + fe
  k_fe<<<64, 256, 0, stream>>>(x2, pe1, pe2, wfet, b_fe, g_fe, be_fe, feb);
  // 6) relation heads
  k_rc<<<NR * NB, 256, 0, stream>>>(feb, wrt, b_rc1, g_rc, be_rc, w_rc2, b_rc2,
                                    plab, out + ZOFF, rel);
  // 7) total
  k_fin<<<1, 64, 0, stream>>>(crfb, rel, out);
}

// Round 10
// 398.164 us; speedup vs baseline: 1.0862x; 1.0862x over previous
//
#include <hip/hip_runtime.h>
#include <math.h>

// Problem: NERRelationModel_84963043050124
// B=64 S=512 H=768 E=32 P=16 K=9 R=6 HEADS=4 C1=128 C2=64 FEAT=257
// Outputs: ner_logits [B,S,K]=294912, z [R,B,P]=6144, total [1] -> 301057 f32

#define NB 64
#define NS 512
#define NH 768
#define NE 32
#define NP 16
#define NK 9
#define NR 6
#define NHEADS 4
#define NC1 128
#define NC2 64
#define SEGS 16
#define SEGLEN 32

#define ZOFF 294912
#define TOTOFF 301056

// ---- workspace layout (float offsets) ----
#define WS_ENT   0u           // bf16 entb [B,E,768] (dead after k_g1f -> WRT/WFET/SEG)
#define WS_WG1T  1572864u     // bf16 wg1t [512][768]
#define WS_X1    2621440u     // bf16 x1b [B,E,512]
#define WS_X2    3801088u     // f32 [B,E,64]
#define WS_WG2T  3956736u     // bf16 wg2t [64][512]
#define WS_FE    4222976u     // bf16 [B,P,512]
#define WS_CRF   4747264u     // [64]
#define WS_REL   4747328u     // [1]
#define WS_W1T   4747392u     // bf16 [256][768]
// overlapped into dead ENT region (valid after k_g1f consumed entb):
#define WS_WRT   0u           // bf16 [R*256][512]
#define WS_WFET  393216u      // bf16 [512][320]
#define WS_SEG   475136u      // f32 [B][SEGS][81]

typedef __attribute__((ext_vector_type(8))) short bf16x8;
typedef __attribute__((ext_vector_type(4))) float f32x4;

__device__ __forceinline__ unsigned short f2bf(float x) {
  union { float f; unsigned u; } v; v.f = x;
  unsigned r = v.u + 0x7FFFu + ((v.u >> 16) & 1u);
  return (unsigned short)(r >> 16);
}

__device__ __forceinline__ float logsigf(float x) {
  if (x >= 0.f) return -log1pf(__expf(-x));
  return x - log1pf(__expf(x));
}

// ---------------- k_prep: weight transposes (w_ner1/w_gat1/w_gat2) + entity pool ----------------
__global__ __launch_bounds__(256) void k_prep(
    const float* __restrict__ w1, const float* __restrict__ wg1,
    const float* __restrict__ wg2, const float* __restrict__ seq,
    const int* __restrict__ est, const int* __restrict__ elen,
    unsigned short* __restrict__ w1t, unsigned short* __restrict__ wg1t,
    unsigned short* __restrict__ wg2t, unsigned short* __restrict__ entb) {
  __shared__ unsigned short tr[32 * 776];  // [col-in-tile][k]
  const int bid = blockIdx.x, t = threadIdx.x;
  if (bid < 26) {
    const float* src;
    unsigned short* dst;
    int c0, ncol, nkt, kdim;
    if (bid < 8)       { src = w1;  dst = w1t;  ncol = 256; c0 = bid * 32;        nkt = 24; kdim = 768; }
    else if (bid < 24) { src = wg1; dst = wg1t; ncol = 512; c0 = (bid - 8) * 32;  nkt = 24; kdim = 768; }
    else               { src = wg2; dst = wg2t; ncol = 64;  c0 = (bid - 24) * 32; nkt = 16; kdim = 512; }
    for (int p = 0; p < nkt; p++) {
      const int k = p * 32 + (t >> 3), c4 = t & 7;
      const float4 f = *reinterpret_cast<const float4*>(&src[(size_t)k * ncol + c0 + c4 * 4]);
      tr[(c4 * 4 + 0) * 776 + k] = f2bf(f.x);
      tr[(c4 * 4 + 1) * 776 + k] = f2bf(f.y);
      tr[(c4 * 4 + 2) * 776 + k] = f2bf(f.z);
      tr[(c4 * 4 + 3) * 776 + k] = f2bf(f.w);
    }
    __syncthreads();
    const int c = t >> 3, q = t & 7;
    const int chunk = kdim >> 3;  // 96 or 64 k per q
    for (int i = 0; i < (chunk >> 3); i++) {
      *reinterpret_cast<uint4*>(&dst[(size_t)(c0 + c) * kdim + q * chunk + i * 8]) =
          *reinterpret_cast<const uint4*>(&tr[c * 776 + q * chunk + i * 8]);
    }
  } else {
    const int be = bid - 26;
    const int b = be >> 5, e = be & 31;
    const int st = est[b * NE + e];
    int en = st + elen[b * NE + e];
    en = min(max(en, 0), NS - 1);
    const float inv = 1.f / (float)(en - st + 1);
    for (int c = t; c < NH; c += 256) {
      float s = 0.f;
      for (int r = st; r <= en; r++) s += seq[((size_t)b * NS + r) * NH + c];
      entb[((size_t)b * NE + e) * NH + c] = f2bf(s * inv);
    }
  }
}

// ---------------- fused GAT1 (standalone, R8-proven): MFMA GEMM + dots + softmax + aggregate + relu ----------------
__global__ __launch_bounds__(256) void k_g1f(
    const unsigned short* __restrict__ entb, const unsigned short* __restrict__ wg1t,
    const float* __restrict__ as1, const float* __restrict__ ad1,
    const unsigned char* __restrict__ adj, const float* __restrict__ bias1,
    unsigned short* __restrict__ x1b) {
  __shared__ unsigned short As[32 * 40];
  __shared__ unsigned short Bs[128 * 40];
  __shared__ float Hs[32 * 132];
  __shared__ float Att[32 * 32];   // [j][i]
  __shared__ float Sv[32], Dv[32];
  const int bid = blockIdx.x, t = threadIdx.x;
  const int w = t >> 6, lane = t & 63, quad = lane >> 4, l15 = lane & 15;
  const int b = bid >> 2, hd = bid & 3;

  f32x4 acc[2][2];
#pragma unroll
  for (int r = 0; r < 2; r++)
#pragma unroll
    for (int c = 0; c < 2; c++) acc[r][c] = (f32x4){0.f, 0.f, 0.f, 0.f};

  const int rowA = t >> 2, koffA = (t & 3) * 8;  // t<128 stages A
  const unsigned short* aptr = entb + ((size_t)(b * NE) + rowA) * NH + koffA;

  for (int kt = 0; kt < NH; kt += 32) {
    __syncthreads();
    if (t < 128) {
      *reinterpret_cast<uint4*>(&As[rowA * 40 + koffA]) =
          *reinterpret_cast<const uint4*>(aptr + kt);
    }
#pragma unroll
    for (int i = 0; i < 2; i++) {
      const int q = t + 256 * i;
      const int col = q >> 2, koff = (q & 3) * 8;
      *reinterpret_cast<uint4*>(&Bs[col * 40 + koff]) =
          *reinterpret_cast<const uint4*>(&wg1t[(size_t)(hd * 128 + col) * NH + kt + koff]);
    }
    __syncthreads();
    bf16x8 a[2], bb[2];
#pragma unroll
    for (int r = 0; r < 2; r++)
      a[r] = *reinterpret_cast<const bf16x8*>(&As[(r * 16 + l15) * 40 + quad * 8]);
#pragma unroll
    for (int c = 0; c < 2; c++)
      bb[c] = *reinterpret_cast<const bf16x8*>(&Bs[(w * 32 + c * 16 + l15) * 40 + quad * 8]);
#pragma unroll
    for (int r = 0; r < 2; r++)
#pragma unroll
      for (int c = 0; c < 2; c++)
        acc[r][c] = __builtin_amdgcn_mfma_f32_16x16x32_bf16(a[r], bb[c], acc[r][c], 0, 0, 0);
  }
#pragma unroll
  for (int r = 0; r < 2; r++)
#pragma unroll
    for (int c = 0; c < 2; c++)
#pragma unroll
      for (int reg = 0; reg < 4; reg++)
        Hs[(r * 16 + quad * 4 + reg) * 132 + w * 32 + c * 16 + l15] = acc[r][c][reg];
  __syncthreads();
  {
    const int e = t >> 3, cg = t & 7;
    float sv = 0.f, dv = 0.f;
#pragma unroll
    for (int c = 0; c < 16; c++) {
      const float h = Hs[e * 132 + cg * 16 + c];
      sv += h * as1[hd * NC1 + cg * 16 + c];
      dv += h * ad1[hd * NC1 + cg * 16 + c];
    }
#pragma unroll
    for (int o = 1; o < 8; o <<= 1) { sv += __shfl_xor(sv, o); dv += __shfl_xor(dv, o); }
    if (cg == 0) { Sv[e] = sv; Dv[e] = dv; }
  }
  __syncthreads();
  if (t < 32) {
    const int i = t;
    const float di = Dv[i];
    float lg[32];
    float m = -1e30f;
#pragma unroll
    for (int j = 0; j < 32; j++) {
      float v = di + Sv[j];
      v = v >= 0.f ? v : 0.2f * v;
      if (!adj[((size_t)b * NE + i) * NE + j]) v = -1e9f;
      lg[j] = v; m = fmaxf(m, v);
    }
    float sum = 0.f;
#pragma unroll
    for (int j = 0; j < 32; j++) { lg[j] = __expf(lg[j] - m); sum += lg[j]; }
    const float inv = 1.f / sum;
#pragma unroll
    for (int j = 0; j < 32; j++) Att[j * 32 + i] = lg[j] * inv;
  }
  __syncthreads();
  {
    const int tc = t & 31, tr2 = t >> 5;
#pragma unroll
    for (int i = 0; i < 4; i++) {
      const int row = tr2 * 4 + i;
      float o0 = bias1[hd * NC1 + tc * 4 + 0];
      float o1 = bias1[hd * NC1 + tc * 4 + 1];
      float o2 = bias1[hd * NC1 + tc * 4 + 2];
      float o3 = bias1[hd * NC1 + tc * 4 + 3];
#pragma unroll
      for (int j = 0; j < 32; j++) {
        const float a = Att[j * 32 + row];
        o0 = fmaf(a, Hs[j * 132 + tc * 4 + 0], o0);
        o1 = fmaf(a, Hs[j * 132 + tc * 4 + 1], o1);
        o2 = fmaf(a, Hs[j * 132 + tc * 4 + 2], o2);
        o3 = fmaf(a, Hs[j * 132 + tc * 4 + 3], o3);
      }
      uint2 v;
      v.x = (unsigned)f2bf(fmaxf(o0, 0.f)) | ((unsigned)f2bf(fmaxf(o1, 0.f)) << 16);
      v.y = (unsigned)f2bf(fmaxf(o2, 0.f)) | ((unsigned)f2bf(fmaxf(o3, 0.f)) << 16);
      *reinterpret_cast<uint2*>(&x1b[((size_t)b * NE + row) * 512 + hd * 128 + tc * 4]) = v;
    }
  }
}

// ---------------- NER head (standalone, R8-proven): MFMA bf16, 32-token x 256-col tiles ----------------
__global__ __launch_bounds__(256) void k_ner(const float* __restrict__ seq,
    const unsigned short* __restrict__ w1t, const float* __restrict__ b1,
    const float* __restrict__ w2, const float* __restrict__ b2,
    float* __restrict__ out) {
  __shared__ unsigned short AsS[32 * 40];
  __shared__ unsigned short BsS[256 * 40];
  __shared__ float zs[32 * 4 * 12];
  const int t = threadIdx.x;
  const int tok0 = blockIdx.x * 32;
  const int w = t >> 6, lane = t & 63, quad = lane >> 4, l15 = lane & 15;

  f32x4 acc[2][4];
#pragma unroll
  for (int r = 0; r < 2; r++)
#pragma unroll
    for (int c = 0; c < 4; c++) acc[r][c] = (f32x4){0.f, 0.f, 0.f, 0.f};

  const int tokA = t >> 3, koffA = (t & 7) * 4;  // 4 floats per thread
  const float* aptr = seq + (size_t)(tok0 + tokA) * NH + koffA;

  for (int kt = 0; kt < NH; kt += 32) {
    __syncthreads();
    {
      const float4 f0 = *reinterpret_cast<const float4*>(aptr + kt);
      uint2 v;
      v.x = (unsigned)f2bf(f0.x) | ((unsigned)f2bf(f0.y) << 16);
      v.y = (unsigned)f2bf(f0.z) | ((unsigned)f2bf(f0.w) << 16);
      *reinterpret_cast<uint2*>(&AsS[tokA * 40 + koffA]) = v;
    }
#pragma unroll
    for (int i = 0; i < 4; i++) {
      const int q = t + 256 * i;
      const int col = q >> 2, koff = (q & 3) * 8;
      *reinterpret_cast<uint4*>(&BsS[col * 40 + koff]) =
          *reinterpret_cast<const uint4*>(&w1t[(size_t)col * NH + kt + koff]);
    }
    __syncthreads();
    bf16x8 a[2], b[4];
#pragma unroll
    for (int r = 0; r < 2; r++)
      a[r] = *reinterpret_cast<const bf16x8*>(&AsS[(r * 16 + l15) * 40 + quad * 8]);
#pragma unroll
    for (int c = 0; c < 4; c++)
      b[c] = *reinterpret_cast<const bf16x8*>(&BsS[(w * 64 + c * 16 + l15) * 40 + quad * 8]);
#pragma unroll
    for (int r = 0; r < 2; r++)
#pragma unroll
      for (int c = 0; c < 4; c++)
        acc[r][c] = __builtin_amdgcn_mfma_f32_16x16x32_bf16(a[r], b[c], acc[r][c], 0, 0, 0);
  }

  float b1v[4], w2v[4][NK];
#pragma unroll
  for (int c = 0; c < 4; c++) {
    const int col = w * 64 + c * 16 + l15;
    b1v[c] = b1[col];
#pragma unroll
    for (int cc = 0; cc < NK; cc++) w2v[c][cc] = w2[col * NK + cc];
  }
#pragma unroll
  for (int r = 0; r < 2; r++) {
#pragma unroll
    for (int reg = 0; reg < 4; reg++) {
      float p[NK];
#pragma unroll
      for (int cc = 0; cc < NK; cc++) p[cc] = 0.f;
#pragma unroll
      for (int c = 0; c < 4; c++) {
        const float h = fmaxf(acc[r][c][reg] + b1v[c], 0.f);
#pragma unroll
        for (int cc = 0; cc < NK; cc++) p[cc] = fmaf(h, w2v[c][cc], p[cc]);
      }
#pragma unroll
      for (int o = 1; o < 16; o <<= 1)
#pragma unroll
        for (int cc = 0; cc < NK; cc++) p[cc] += __shfl_xor(p[cc], o);
      if (l15 == 0) {
        const int tokr = r * 16 + quad * 4 + reg;
#pragma unroll
        for (int cc = 0; cc < NK; cc++) zs[(tokr * 4 + w) * 12 + cc] = p[cc];
      }
    }
  }
  __syncthreads();
  if (t < 32) {
#pragma unroll
    for (int cc = 0; cc < NK; cc++) {
      const float z = zs[(t * 4 + 0) * 12 + cc] + zs[(t * 4 + 1) * 12 + cc] +
                      zs[(t * 4 + 2) * 12 + cc] + zs[(t * 4 + 3) * 12 + cc] + b2[cc];
      out[(size_t)(tok0 + t) * NK + cc] = z;
    }
  }
}

// ---------------- k_mid: weight converts (blocks 0..57) + CRF segment reduce (58..1081) ----------------
// CRF log-semiring products exp-factored (R9-verified): 162 exp + 729 fma vs 729 exp.
__global__ __launch_bounds__(256) void k_mid(
    const float* __restrict__ wrc, const float* __restrict__ wfe,
    unsigned short* __restrict__ wrt, unsigned short* __restrict__ wfet,
    const float* __restrict__ em, const int* __restrict__ mask,
    const float* __restrict__ trans, float* __restrict__ segm) {
  __shared__ __align__(16) char smem[36864];
  const int bid = blockIdx.x, t = threadIdx.x;
  if (bid < 58) {
    unsigned short* tr = (unsigned short*)smem;  // [256*72]
    if (bid < 48) {
      const int r = bid >> 3, kt = bid & 7;
      const int k0 = kt * 64;
#pragma unroll
      for (int i = 0; i < 16; i++) {
        const int slot = t + 256 * i;
        const int row = slot >> 6, c4 = slot & 63;
        const float4 f = *reinterpret_cast<const float4*>(
            &wrc[((size_t)(r * 512) + k0 + row) * 256 + c4 * 4]);
        tr[(c4 * 4 + 0) * 72 + row] = f2bf(f.x);
        tr[(c4 * 4 + 1) * 72 + row] = f2bf(f.y);
        tr[(c4 * 4 + 2) * 72 + row] = f2bf(f.z);
        tr[(c4 * 4 + 3) * 72 + row] = f2bf(f.w);
      }
      __syncthreads();
#pragma unroll
      for (int i = 0; i < 8; i++) {
        const int slot = t + 256 * i;
        const int col = slot >> 3, q = slot & 7;
        *reinterpret_cast<uint4*>(&wrt[((size_t)(r * 256 + col)) * 512 + k0 + q * 8]) =
            *reinterpret_cast<const uint4*>(&tr[col * 72 + q * 8]);
      }
    } else {
      const int b2 = bid - 48;
      const int kt = b2 % 5, cb = b2 / 5;
      const int k0 = kt * 64, c0 = cb * 256;
#pragma unroll
      for (int i = 0; i < 16; i++) {
        const int slot = t + 256 * i;
        const int row = slot >> 6, c4 = slot & 63;
        const int k = k0 + row;
        float4 f = {0.f, 0.f, 0.f, 0.f};
        if (k < 257)
          f = *reinterpret_cast<const float4*>(&wfe[(size_t)k * 512 + c0 + c4 * 4]);
        tr[(c4 * 4 + 0) * 72 + row] = f2bf(f.x);
        tr[(c4 * 4 + 1) * 72 + row] = f2bf(f.y);
        tr[(c4 * 4 + 2) * 72 + row] = f2bf(f.z);
        tr[(c4 * 4 + 3) * 72 + row] = f2bf(f.w);
      }
      __syncthreads();
#pragma unroll
      for (int i = 0; i < 8; i++) {
        const int slot = t + 256 * i;
        const int col = slot >> 3, q = slot & 7;
        *reinterpret_cast<uint4*>(&wfet[((size_t)(c0 + col)) * 320 + k0 + q * 8]) =
            *reinterpret_cast<const uint4*>(&tr[col * 72 + q * 8]);
      }
    }
  } else {
    float* bufA = (float*)smem;              // [16*81]
    float* bufB = (float*)(smem + 5184);     // [8*81]
    float* EA   = (float*)(smem + 7776);     // [8*81]
    float* EB   = (float*)(smem + 10368);    // [8*81]
    float* Gf   = (float*)(smem + 12960);    // [16*81]
    float* ems  = (float*)(smem + 18144);    // [32*9]
    float* trs  = (float*)(smem + 19296);    // [81]
    float* Hexp = (float*)(smem + 19620);    // [81]
    float* mxp  = (float*)(smem + 19944);    // [16*9]
    float* mxA  = (float*)(smem + 20520);    // [8*9]
    float* mxB  = (float*)(smem + 20808);    // [8*9]
    int*   mks  = (int*)(smem + 21096);      // [32]
    const int blk = bid - 58;
    const int b = blk >> 4, seg = blk & 15;
    const int s0 = 1 + seg * SEGLEN;
    const float* emb = em + (size_t)b * NS * NK;
    const int* mk = mask + b * NS;
    if (t < 81) { trs[t] = trans[t]; Hexp[t] = __expf(trans[t]); }
    for (int i = t; i < SEGLEN * 9; i += 256) {
      const int g = s0 * 9 + i;
      ems[i] = (g < NS * 9) ? emb[g] : 0.f;
    }
    if (t < SEGLEN) {
      const int s = s0 + t;
      mks[t] = (s < NS) ? mk[s] : 0;
    }
    __syncthreads();
    for (int idx = t; idx < 144; idx += 256) {
      const int p = idx / 9, i = idx - p * 9;
      const float* eml = &ems[(2 * p) * 9];
      float mx = -1e30f;
#pragma unroll
      for (int m = 0; m < 9; m++) mx = fmaxf(mx, trs[i * 9 + m] + eml[m]);
      mxp[idx] = mx;
    }
    __syncthreads();
    for (int idx = t; idx < 1296; idx += 256) {
      const int p = idx / 81, r81 = idx - p * 81, i = r81 / 9, m = r81 - i * 9;
      Gf[idx] = __expf(trs[i * 9 + m] + ems[(2 * p) * 9 + m] - mxp[p * 9 + i]);
    }
    __syncthreads();
    for (int idx = t; idx < 1296; idx += 256) {
      const int p = idx / 81, e = idx - p * 81, i = e / 9, j = e - i * 9;
      const int la = 2 * p, lb = la + 1;
      const bool ma = mks[la] > 0, mb = mks[lb] > 0;
      float r;
      if (ma && mb) {
        float s = 0.f;
#pragma unroll
        for (int m = 0; m < 9; m++) s = fmaf(Gf[p * 81 + i * 9 + m], Hexp[m * 9 + j], s);
        r = mxp[p * 9 + i] + __logf(s) + ems[lb * 9 + j];
      } else if (ma) {
        r = trs[e] + ems[la * 9 + j];
      } else if (mb) {
        r = trs[e] + ems[lb * 9 + j];
      } else {
        r = (i == j) ? 0.f : -1e30f;
      }
      bufA[idx] = r;
    }
    float* src = bufA;
    float* dst = bufB;
    for (int n = 16; n > 1; n >>= 1) {
      const int half = n >> 1;
      __syncthreads();
      for (int idx = t; idx < half * 18; idx += 256) {
        const int q = idx / 18, r2 = idx - q * 18;
        if (r2 < 9) {
          const float* A = src + (size_t)(2 * q) * 81 + r2 * 9;
          float mx = -1e30f;
#pragma unroll
          for (int m = 0; m < 9; m++) mx = fmaxf(mx, A[m]);
          mxA[q * 9 + r2] = mx;
        } else {
          const int j = r2 - 9;
          const float* Bm = src + (size_t)(2 * q + 1) * 81;
          float mx = -1e30f;
#pragma unroll
          for (int m = 0; m < 9; m++) mx = fmaxf(mx, Bm[m * 9 + j]);
          mxB[q * 9 + j] = mx;
        }
      }
      __syncthreads();
      for (int idx = t; idx < half * 81; idx += 256) {
        const int q = idx / 81, e = idx - q * 81, i = e / 9, c = e - i * 9;
        EA[idx] = __expf(src[(size_t)(2 * q) * 81 + e] - mxA[q * 9 + i]);
        EB[idx] = __expf(src[(size_t)(2 * q + 1) * 81 + e] - mxB[q * 9 + c]);
      }
      __syncthreads();
      for (int idx = t; idx < half * 81; idx += 256) {
        const int q = idx / 81, e = idx - q * 81, i = e / 9, j = e - i * 9;
        float s = 0.f;
#pragma unroll
        for (int m = 0; m < 9; m++) s = fmaf(EA[q * 81 + i * 9 + m], EB[q * 81 + m * 9 + j], s);
        dst[idx] = mxA[q * 9 + i] + mxB[q * 9 + j] + __logf(s);
      }
      float* tmp = src; src = dst; dst = tmp;
    }
    __syncthreads();
    if (t < 81) segm[((size_t)b * SEGS + seg) * 81 + t] = src[t];
  }
}

// ---------------- k_late: fused GAT2 MFMA (blocks 0..63) + CRF finalize (64..127) ----------------
__global__ __launch_bounds__(256) void k_late(
    const unsigned short* __restrict__ x1b, const unsigned short* __restrict__ wg2t,
    const float* __restrict__ as2, const float* __restrict__ ad2,
    const unsigned char* __restrict__ adj, const float* __restrict__ bias2,
    float* __restrict__ x2,
    const float* __restrict__ em, const int* __restrict__ tags,
    const int* __restrict__ mask, const float* __restrict__ startv,
    const float* __restrict__ endv, const float* __restrict__ trans,
    const float* __restrict__ segm, float* __restrict__ lossb) {
  __shared__ __align__(16) char smem[20736];
  const int bid = blockIdx.x, t = threadIdx.x;
  if (bid < 64) {
    unsigned short* As = (unsigned short*)smem;           // [32*40]
    unsigned short* Bs = (unsigned short*)(smem + 2560);  // [64*40]
    float* H2  = (float*)(smem + 7680);                   // [32*68]
    float* Att = (float*)(smem + 16384);                  // [32*32] ([j][i])
    float* Sv  = (float*)(smem + 20480);                  // [32]
    float* Dv  = (float*)(smem + 20608);                  // [32]
    const int b = bid;
    const int w = t >> 6, lane = t & 63, quad = lane >> 4, l15 = lane & 15;

    f32x4 acc[2];
#pragma unroll
    for (int r = 0; r < 2; r++) acc[r] = (f32x4){0.f, 0.f, 0.f, 0.f};

    const int rowA = t >> 2, koffA = (t & 3) * 8;  // t<128 stages A
    const unsigned short* aptr = x1b + ((size_t)(b * NE) + rowA) * 512 + koffA;

    for (int kt = 0; kt < 512; kt += 32) {
      __syncthreads();
      if (t < 128) {
        *reinterpret_cast<uint4*>(&As[rowA * 40 + koffA]) =
            *reinterpret_cast<const uint4*>(aptr + kt);
      }
      {
        const int col = t >> 2, koff = (t & 3) * 8;  // 64 cols x 4 chunks
        *reinterpret_cast<uint4*>(&Bs[col * 40 + koff]) =
            *reinterpret_cast<const uint4*>(&wg2t[(size_t)col * 512 + kt + koff]);
      }
      __syncthreads();
      const bf16x8 a0 = *reinterpret_cast<const bf16x8*>(&As[l15 * 40 + quad * 8]);
      const bf16x8 a1 = *reinterpret_cast<const bf16x8*>(&As[(16 + l15) * 40 + quad * 8]);
      const bf16x8 bb = *reinterpret_cast<const bf16x8*>(&Bs[(w * 16 + l15) * 40 + quad * 8]);
      acc[0] = __builtin_amdgcn_mfma_f32_16x16x32_bf16(a0, bb, acc[0], 0, 0, 0);
      acc[1] = __builtin_amdgcn_mfma_f32_16x16x32_bf16(a1, bb, acc[1], 0, 0, 0);
    }
#pragma unroll
    for (int r = 0; r < 2; r++)
#pragma unroll
      for (int reg = 0; reg < 4; reg++)
        H2[(r * 16 + quad * 4 + reg) * 68 + w * 16 + l15] = acc[r][reg];
    __syncthreads();
    {
      const int e = t >> 3, cg = t & 7;
      float sv = 0.f, dv = 0.f;
#pragma unroll
      for (int c = 0; c < 8; c++) {
        const float h = H2[e * 68 + cg * 8 + c];
        sv += h * as2[cg * 8 + c];
        dv += h * ad2[cg * 8 + c];
      }
#pragma unroll
      for (int o = 1; o < 8; o <<= 1) { sv += __shfl_xor(sv, o); dv += __shfl_xor(dv, o); }
      if (cg == 0) { Sv[e] = sv; Dv[e] = dv; }
    }
    __syncthreads();
    if (t < 32) {
      const int i = t;
      const float di = Dv[i];
      float m = -1e30f;
      for (int j = 0; j < 32; j++) {
        float v = di + Sv[j];
        v = v >= 0.f ? v : 0.2f * v;
        if (!adj[((size_t)b * NE + i) * NE + j]) v = -1e9f;
        Att[j * 32 + i] = v;
        m = fmaxf(m, v);
      }
      float sum = 0.f;
      for (int j = 0; j < 32; j++) {
        const float e = __expf(Att[j * 32 + i] - m);
        Att[j * 32 + i] = e;
        sum += e;
      }
      const float inv = 1.f / sum;
      for (int j = 0; j < 32; j++) Att[j * 32 + i] *= inv;
    }
    __syncthreads();
    {
      const int tc = t & 15, tr2 = t >> 4;
#pragma unroll
      for (int i = 0; i < 2; i++) {
        const int row = tr2 * 2 + i;
        float o0 = bias2[tc * 4 + 0];
        float o1 = bias2[tc * 4 + 1];
        float o2 = bias2[tc * 4 + 2];
        float o3 = bias2[tc * 4 + 3];
#pragma unroll
        for (int j = 0; j < 32; j++) {
          const float a = Att[j * 32 + row];
          o0 = fmaf(a, H2[j * 68 + tc * 4 + 0], o0);
          o1 = fmaf(a, H2[j * 68 + tc * 4 + 1], o1);
          o2 = fmaf(a, H2[j * 68 + tc * 4 + 2], o2);
          o3 = fmaf(a, H2[j * 68 + tc * 4 + 3], o3);
        }
        float4 v;
        v.x = o0; v.y = o1; v.z = o2; v.w = o3;
        *reinterpret_cast<float4*>(&x2[((size_t)b * NE + row) * NC2 + tc * 4]) = v;
      }
    }
  } else {
    float* sm  = (float*)smem;            // [SEGS*81]
    float* av  = (float*)(smem + 5184);   // [16]
    float* red = (float*)(smem + 5248);   // [2]
    const int b = bid - 64;
    const float* emb = em + (size_t)b * NS * NK;
    const int* mk = mask + b * NS;
    const int* tg = tags + b * NS;
    for (int i = t; i < SEGS * 81; i += 256) sm[i] = segm[(size_t)b * SEGS * 81 + i];
    if (t < 64) {
      float num = 0.f;
      int lastS = 0;
#pragma unroll
      for (int o = 0; o < 8; o++) {
        const int s = t * 8 + o;
        if (s >= 1 && mk[s] > 0) {
          const int cur = tg[s], prv = tg[s - 1];
          num += trans[prv * NK + cur] + emb[s * NK + cur];
          lastS = s;
        }
      }
#pragma unroll
      for (int o = 32; o > 0; o >>= 1) {
        num += __shfl_xor(num, o);
        lastS = max(lastS, __shfl_xor(lastS, o));
      }
      if (t == 0) {
        const int t0 = tg[0];
        red[0] = startv[t0] + emb[t0] + num + endv[tg[lastS]];
      }
    }
    __syncthreads();
    if (t < 9) av[t] = startv[t] + emb[t];
    __syncthreads();
    for (int h = 0; h < SEGS; h++) {
      float nv = 0.f;
      if (t < 9) {
        float v[9], mx = -1e30f;
#pragma unroll
        for (int i2 = 0; i2 < 9; i2++) {
          v[i2] = av[i2] + sm[h * 81 + i2 * 9 + t];
          mx = fmaxf(mx, v[i2]);
        }
        float sum = 0.f;
#pragma unroll
        for (int i2 = 0; i2 < 9; i2++) sum += __expf(v[i2] - mx);
        nv = mx + __logf(sum);
      }
      __syncthreads();
      if (t < 9) av[t] = nv;
      __syncthreads();
    }
    if (t == 0) {
      float mx = -1e30f;
#pragma unroll
      for (int j = 0; j < 9; j++) mx = fmaxf(mx, av[j] + endv[j]);
      float sum = 0.f;
#pragma unroll
      for (int j = 0; j < 9; j++) sum += __expf(av[j] + endv[j] - mx);
      lossb[b] = (mx + __logf(sum)) - red[0];
    }
  }
}

// ---------------- k_fe: pair-features (inlined) + MFMA + LN + leaky, bf16 out ----------------
__global__ __launch_bounds__(256) void k_fe(const float* __restrict__ x2,
    const int* __restrict__ pe1, const int* __restrict__ pe2,
    const unsigned short* __restrict__ wt, const float* __restrict__ bfe,
    const float* __restrict__ g, const float* __restrict__ be,
    unsigned short* __restrict__ feb) {
  __shared__ unsigned short Af[16 * 320];
  __shared__ float Cs[16 * 520];
  __shared__ float ctxs[64];
  const int b = blockIdx.x, t = threadIdx.x;
  const int w = t >> 6, lane = t & 63, quad = lane >> 4, l15 = lane & 15;
  if (t < 64) {
    float cs = 0.f;
    for (int e = 0; e < NE; e++) cs += x2[((size_t)b * NE + e) * NC2 + t];
    ctxs[t] = cs * (1.f / NE);
  }
  __syncthreads();
  for (int i = t; i < 16 * 320; i += 256) {
    const int p = i / 320, k = i - p * 320;
    unsigned short o = 0;
    if (k < 260) {
      const int e1 = pe1[b * NP + p], e2 = pe2[b * NP + p];
      float v;
      if (k < 64) v = x2[((size_t)b * NE + e1) * NC2 + k];
      else if (k < 128) v = x2[((size_t)b * NE + e2) * NC2 + (k - 64)];
      else if (k < 192) v = x2[((size_t)b * NE + e1) * NC2 + (k - 128)] *
                            x2[((size_t)b * NE + e2) * NC2 + (k - 128)];
      else if (k < 256) v = ctxs[k - 192];
      else if (k == 256) v = logf(fabsf((float)(e1 - e2)) + 1.f);
      else v = 0.f;
      o = f2bf(v);
    }
    Af[i] = o;
  }
  __syncthreads();
  f32x4 acc[8];
#pragma unroll
  for (int c = 0; c < 8; c++) acc[c] = (f32x4){0.f, 0.f, 0.f, 0.f};
#pragma unroll
  for (int kt = 0; kt < 10; kt++) {
    const bf16x8 a = *reinterpret_cast<const bf16x8*>(&Af[l15 * 320 + kt * 32 + quad * 8]);
#pragma unroll
    for (int c = 0; c < 8; c++) {
      const int col = w * 128 + c * 16 + l15;
      const bf16x8 bv = *reinterpret_cast<const bf16x8*>(&wt[(size_t)col * 320 + kt * 32 + quad * 8]);
      acc[c] = __builtin_amdgcn_mfma_f32_16x16x32_bf16(a, bv, acc[c], 0, 0, 0);
    }
  }
#pragma unroll
  for (int c = 0; c < 8; c++)
#pragma unroll
    for (int reg = 0; reg < 4; reg++)
      Cs[(quad * 4 + reg) * 520 + w * 128 + c * 16 + l15] = acc[c][reg];
  __syncthreads();
  float bfev[8], gv[8], bev[8];
#pragma unroll
  for (int ch = 0; ch < 8; ch++) {
    const int col = ch * 64 + lane;
    bfev[ch] = bfe[col]; gv[ch] = g[col]; bev[ch] = be[col];
  }
#pragma unroll
  for (int pp = 0; pp < 4; pp++) {
    const int p = w * 4 + pp;
    float v[8], s = 0.f, sq = 0.f;
#pragma unroll
    for (int ch = 0; ch < 8; ch++) {
      v[ch] = Cs[p * 520 + ch * 64 + lane] + bfev[ch];
      s += v[ch]; sq += v[ch] * v[ch];
    }
#pragma unroll
    for (int o = 32; o > 0; o >>= 1) { s += __shfl_xor(s, o); sq += __shfl_xor(sq, o); }
    const float mean = s * (1.f / 512.f);
    const float var = sq * (1.f / 512.f) - mean * mean;
    const float rr = rsqrtf(var + 1e-5f);
#pragma unroll
    for (int ch = 0; ch < 8; ch++) {
      float n = (v[ch] - mean) * rr * gv[ch] + bev[ch];
      n = n >= 0.f ? n : 0.01f * n;
      feb[(size_t)(b * NP + p) * 512 + ch * 64 + lane] = f2bf(n);
    }
  }
}

// ---------------- relation heads: MFMA bf16 GEMM + LN + leaky + dot + BCE ----------------
__global__ __launch_bounds__(256) void k_rc(const unsigned short* __restrict__ feb,
    const unsigned short* __restrict__ wrt, const float* __restrict__ b1,
    const float* __restrict__ g, const float* __restrict__ be,
    const float* __restrict__ w2, const float* __restrict__ b2,
    const int* __restrict__ ylab, float* __restrict__ zout, float* __restrict__ relacc) {
  __shared__ unsigned short Af[16 * 520];
  __shared__ float Cs[16 * 264];
  const int blk = blockIdx.x;
  const int r = blk >> 6, b = blk & 63;
  const int t = threadIdx.x;
  const int w = t >> 6, lane = t & 63, quad = lane >> 4, l15 = lane & 15;
#pragma unroll
  for (int i = 0; i < 4; i++) {
    const int slot = t + 256 * i;
    const int p = slot >> 6, q = slot & 63;
    *reinterpret_cast<uint4*>(&Af[p * 520 + q * 8]) =
        *reinterpret_cast<const uint4*>(&feb[(size_t)(b * NP + p) * 512 + q * 8]);
  }
  __syncthreads();
  f32x4 acc[4];
#pragma unroll
  for (int c = 0; c < 4; c++) acc[c] = (f32x4){0.f, 0.f, 0.f, 0.f};
#pragma unroll
  for (int kt = 0; kt < 16; kt++) {
    const bf16x8 a = *reinterpret_cast<const bf16x8*>(&Af[l15 * 520 + kt * 32 + quad * 8]);
#pragma unroll
    for (int c = 0; c < 4; c++) {
      const int col = w * 64 + c * 16 + l15;
      const bf16x8 bv = *reinterpret_cast<const bf16x8*>(
          &wrt[(size_t)(r * 256 + col) * 512 + kt * 32 + quad * 8]);
      acc[c] = __builtin_amdgcn_mfma_f32_16x16x32_bf16(a, bv, acc[c], 0, 0, 0);
    }
  }
#pragma unroll
  for (int c = 0; c < 4; c++)
#pragma unroll
    for (int reg = 0; reg < 4; reg++)
      Cs[(quad * 4 + reg) * 264 + w * 64 + c * 16 + l15] = acc[c][reg];
  __syncthreads();
  float b1v[4], gv[4], bev[4], w2v[4];
#pragma unroll
  for (int ch = 0; ch < 4; ch++) {
    const int col = r * 256 + ch * 64 + lane;
    b1v[ch] = b1[col]; gv[ch] = g[col]; bev[ch] = be[col]; w2v[ch] = w2[col];
  }
  const float b2v = b2[r];
  float local = 0.f;
#pragma unroll
  for (int pp = 0; pp < 4; pp++) {
    const int p = w * 4 + pp;
    float v[4], s = 0.f, sq = 0.f;
#pragma unroll
    for (int ch = 0; ch < 4; ch++) {
      v[ch] = Cs[p * 264 + ch * 64 + lane] + b1v[ch];
      s += v[ch]; sq += v[ch] * v[ch];
    }
#pragma unroll
    for (int o = 32; o > 0; o >>= 1) { s += __shfl_xor(s, o); sq += __shfl_xor(sq, o); }
    const float mean = s * (1.f / 256.f);
    const float var = sq * (1.f / 256.f) - mean * mean;
    const float rr = rsqrtf(var + 1e-5f);
    float zdot = 0.f;
#pragma unroll
    for (int ch = 0; ch < 4; ch++) {
      float n = (v[ch] - mean) * rr * gv[ch] + bev[ch];
      n = n >= 0.f ? n : 0.01f * n;
      zdot = fmaf(n, w2v[ch], zdot);
    }
#pragma unroll
    for (int o = 32; o > 0; o >>= 1) zdot += __shfl_xor(zdot, o);
    if (lane == 0) {
      const float zp = zdot + b2v;
      zout[(size_t)(r * NB + b) * NP + p] = zp;
      const float y = (float)ylab[b * NP + p];
      local += -(2.f * y * logsigf(zp) + (1.f - y) * logsigf(-zp));
    }
  }
  if (lane == 0) atomicAdd(relacc, local * (1.f / (NB * NP)));
}

// ---------------- finalize total loss ----------------
__global__ __launch_bounds__(64) void k_fin(const float* __restrict__ lossb,
    const float* __restrict__ rel, float* __restrict__ out) {
  float v = lossb[threadIdx.x];
#pragma unroll
  for (int o = 32; o > 0; o >>= 1) v += __shfl_down(v, o);
  if (threadIdx.x == 0) out[TOTOFF] = v * (1.f / NB) + rel[0];
}

extern "C" void kernel_launch(void* const* d_in, const int* in_sizes, int n_in,
                              void* d_out, int out_size, void* d_ws, size_t ws_size,
                              hipStream_t stream) {
  const float* seq = (const float*)d_in[0];
  const int* amask = (const int*)d_in[1];
  const int* nlab = (const int*)d_in[2];
  const int* est = (const int*)d_in[3];
  const int* elen = (const int*)d_in[4];
  const int* pe1 = (const int*)d_in[5];
  const int* pe2 = (const int*)d_in[6];
  const int* plab = (const int*)d_in[7];
  const unsigned char* adj = (const unsigned char*)d_in[8];
  const float* w_ner1 = (const float*)d_in[9];
  const float* b_ner1 = (const float*)d_in[10];
  const float* w_ner2 = (const float*)d_in[11];
  const float* b_ner2 = (const float*)d_in[12];
  const float* crf_start = (const float*)d_in[13];
  const float* crf_end = (const float*)d_in[14];
  const float* crf_trans = (const float*)d_in[15];
  const float* w_gat1 = (const float*)d_in[16];
  const float* a_src1 = (const float*)d_in[17];
  const float* a_dst1 = (const float*)d_in[18];
  const float* b_gat1 = (const float*)d_in[19];
  const float* w_gat2 = (const float*)d_in[20];
  const float* a_src2 = (const float*)d_in[21];
  const float* a_dst2 = (const float*)d_in[22];
  const float* b_gat2 = (const float*)d_in[23];
  const float* w_fe = (const float*)d_in[24];
  const float* b_fe = (const float*)d_in[25];
  const float* g_fe = (const float*)d_in[26];
  const float* be_fe = (const float*)d_in[27];
  const float* w_rc1 = (const float*)d_in[28];
  const float* b_rc1 = (const float*)d_in[29];
  const float* g_rc = (const float*)d_in[30];
  const float* be_rc = (const float*)d_in[31];
  const float* w_rc2 = (const float*)d_in[32];
  const float* b_rc2 = (const float*)d_in[33];

  float* out = (float*)d_out;
  float* ws = (float*)d_ws;
  float* x2 = ws + WS_X2;
  float* crfb = ws + WS_CRF;
  float* rel = ws + WS_REL;
  unsigned short* entb = (unsigned short*)(ws + WS_ENT);
  unsigned short* wg1t = (unsigned short*)(ws + WS_WG1T);
  unsigned short* wg2t = (unsigned short*)(ws + WS_WG2T);
  unsigned short* x1b = (unsigned short*)(ws + WS_X1);
  unsigned short* w1t = (unsigned short*)(ws + WS_W1T);
  unsigned short* feb = (unsigned short*)(ws + WS_FE);
  unsigned short* wrt = (unsigned short*)(ws + WS_WRT);    // dead ENT region
  unsigned short* wfet = (unsigned short*)(ws + WS_WFET);  // dead ENT region
  float* segm = ws + WS_SEG;                               // dead ENT region

  hipMemsetAsync(rel, 0, sizeof(float), stream);

  // 1) weight transposes + entity pooling (independent)
  k_prep<<<2074, 256, 0, stream>>>(w_ner1, w_gat1, w_gat2, seq, est, elen,
                                   w1t, wg1t, wg2t, entb);
  // 2) GAT1 (own 232-VGPR budget), then NER (own 64-VGPR budget, 4 blocks/CU)
  k_g1f<<<NB * NHEADS, 256, 0, stream>>>(entb, wg1t, a_src1, a_dst1, adj, b_gat1, x1b);
  k_ner<<<1024, 256, 0, stream>>>(seq, w1t, b_ner1, w_ner2, b_ner2, out);
  // 3) weight converts (ENT region now dead) + CRF segment reduce (exp-factored)
  k_mid<<<1082, 256, 0, stream>>>(w_rc1, w_fe, wrt, wfet, out, amask, crf_trans, segm);
  // 4) GAT2 MFMA + CRF finalize, co-resident
  k_late<<<128, 256, 0, stream>>>(x1b, wg2t, a_src2, a_dst2, adj, b_gat2, x2,
                                  out, nlab, amask, crf_start, crf_end, crf_trans,
                                  segm, crfb);
  // 5) pair features (inlined) + fe
  k_fe<<<64, 256, 0, stream>>>(x2, pe1, pe2, wfet, b_fe, g_fe, be_fe, feb);
  // 6) relation heads
  k_rc<<<NR * NB, 256, 0, stream>>>(feb, wrt, b_rc1, g_rc, be_rc, w_rc2, b_rc2,
                                    plab, out + ZOFF, rel);
  // 7) total
  k_fin<<<1, 64, 0, stream>>>(crfb, rel, out);
}